// Round 1
// baseline (1086.078 us; speedup 1.0000x reference)
//
#include <hip/hip_runtime.h>
#include <hip/hip_bf16.h>
#include <math.h>

// GRNN: x (32,2000,512) fp32. Two SRUs on channel halves.
// Phase 1: U = x_half @ W_half (M=64000,K=256,N=768), gates. xt,f -> ws; r -> d_out.
// Phase 2: sequential scan over t per (b,channel) + highway, overwrites d_out.

constexpr int BATCH = 32;
constexpr int TLEN  = 2000;
constexpr int DDIM  = 512;
constexpr int HH    = 256;          // half hidden
constexpr int N3    = 3 * HH;       // 768
constexpr int MROWS = BATCH * TLEN; // 64000

// ---- storage-type helpers (fp32 ws if it fits, bf16 fallback) ----
__device__ __forceinline__ float ldst(const float* p, size_t i) { return p[i]; }
__device__ __forceinline__ float ldst(const __hip_bfloat16* p, size_t i) { return __bfloat162float(p[i]); }
__device__ __forceinline__ void stst(float* p, size_t i, float v) { p[i] = v; }
__device__ __forceinline__ void stst(__hip_bfloat16* p, size_t i, float v) { p[i] = __float2bfloat16(v); }

__device__ __forceinline__ float sigmoidf_(float v) {
    return 1.0f / (1.0f + expf(-v));
}

// ---- Phase 1: tiled fp32 GEMM + gate epilogue ----
// grid: (N3/64, MROWS/64, 2 halves), block: 256 threads, 4x4 per thread.
template <typename ST>
__global__ __launch_bounds__(256) void gemm_gates(
    const float* __restrict__ x,
    const float* __restrict__ W1, const float* __restrict__ bf1, const float* __restrict__ br1,
    const float* __restrict__ W2, const float* __restrict__ bf2, const float* __restrict__ br2,
    ST* __restrict__ xt_ws, ST* __restrict__ f_ws, float* __restrict__ out)
{
    const int half = blockIdx.z;
    const float* __restrict__ W  = half ? W2  : W1;
    const float* __restrict__ bf = half ? bf2 : bf1;
    const float* __restrict__ br = half ? br2 : br1;

    const int n0 = blockIdx.x * 64;   // column within [0,768)
    const int m0 = blockIdx.y * 64;   // row within [0,64000)

    __shared__ float As[32][68];      // [k][m] padded (68*4B = 17x16B banks)
    __shared__ float Bs[32][68];      // [k][n] padded

    const int tid = threadIdx.x;
    const int tx = tid & 15;          // col group (4 cols)
    const int ty = tid >> 4;          // row group (4 rows)

    float acc[4][4];
#pragma unroll
    for (int i = 0; i < 4; ++i)
#pragma unroll
        for (int j = 0; j < 4; ++j) acc[i][j] = 0.f;

    for (int k0 = 0; k0 < HH; k0 += 32) {
        // stage A-tile: 64 rows x 32 k  (512 float4 loads by 256 threads)
#pragma unroll
        for (int l = 0; l < 2; ++l) {
            const int chunk = tid + l * 256;     // 0..511
            const int row = chunk >> 3;          // 0..63
            const int kq  = chunk & 7;           // float4 index in k
            const float4 v = *reinterpret_cast<const float4*>(
                x + (size_t)(m0 + row) * DDIM + half * HH + k0 + kq * 4);
            As[kq * 4 + 0][row] = v.x;
            As[kq * 4 + 1][row] = v.y;
            As[kq * 4 + 2][row] = v.z;
            As[kq * 4 + 3][row] = v.w;
        }
        // stage B-tile: 32 k-rows x 64 cols
#pragma unroll
        for (int l = 0; l < 2; ++l) {
            const int chunk = tid + l * 256;
            const int kr = chunk >> 4;           // 0..31
            const int nq = chunk & 15;           // float4 col group
            const float4 v = *reinterpret_cast<const float4*>(
                W + (size_t)(k0 + kr) * N3 + n0 + nq * 4);
            *reinterpret_cast<float4*>(&Bs[kr][nq * 4]) = v;
        }
        __syncthreads();

#pragma unroll
        for (int kk = 0; kk < 32; ++kk) {
            const float4 av = *reinterpret_cast<const float4*>(&As[kk][ty * 4]);
            const float4 bv = *reinterpret_cast<const float4*>(&Bs[kk][tx * 4]);
            const float a[4] = {av.x, av.y, av.z, av.w};
            const float b[4] = {bv.x, bv.y, bv.z, bv.w};
#pragma unroll
            for (int i = 0; i < 4; ++i)
#pragma unroll
                for (int j = 0; j < 4; ++j)
                    acc[i][j] = __builtin_fmaf(a[i], b[j], acc[i][j]);
        }
        __syncthreads();
    }

    // epilogue: route by segment (block-uniform: 64-wide tile inside 256-wide segment)
    const int seg = n0 >> 8;   // 0: x_tilde, 1: f, 2: r
#pragma unroll
    for (int i = 0; i < 4; ++i) {
        const int row = m0 + ty * 4 + i;
#pragma unroll
        for (int j = 0; j < 4; ++j) {
            const int n = n0 + tx * 4 + j;
            const int hcol = n & 255;
            const size_t idx = (size_t)row * DDIM + half * HH + hcol;
            const float v = acc[i][j];
            if (seg == 0) {
                stst(xt_ws, idx, v);
            } else if (seg == 1) {
                stst(f_ws, idx, sigmoidf_(v + bf[hcol]));
            } else {
                out[idx] = sigmoidf_(v + br[hcol]);   // r stored in d_out
            }
        }
    }
}

// ---- Phase 2: sequential scan + highway ----
// 16384 threads: one per (batch, channel). 256 blocks x 64 -> 1 wave on each CU.
template <typename ST>
__global__ __launch_bounds__(64) void scan_highway(
    const float* __restrict__ x,
    const ST* __restrict__ f_ws, const ST* __restrict__ xt_ws,
    float* __restrict__ out)
{
    const int id = blockIdx.x * 64 + threadIdx.x;   // 0..16383
    const size_t b = (size_t)(id >> 9);
    const int col = id & 511;
    const size_t base = b * TLEN * DDIM + col;

    float c = 0.f;
#pragma unroll 8
    for (int t = 0; t < TLEN; ++t) {
        const size_t idx = base + (size_t)t * DDIM;
        const float f  = ldst(f_ws, idx);
        const float xt = ldst(xt_ws, idx);
        const float r  = out[idx];          // r written by phase 1
        const float xv = x[idx];
        const float u  = __builtin_fmaf(-f, xt, xt);   // (1-f)*xt (indep of chain)
        c = __builtin_fmaf(f, c, u);                    // 1 dependent FMA/step
        out[idx] = __builtin_fmaf(r, c - xv, xv);       // r*c + (1-r)*x
    }
}

extern "C" void kernel_launch(void* const* d_in, const int* in_sizes, int n_in,
                              void* d_out, int out_size, void* d_ws, size_t ws_size,
                              hipStream_t stream)
{
    const float* x   = (const float*)d_in[0];
    const float* W1  = (const float*)d_in[1];
    const float* bf1 = (const float*)d_in[2];
    const float* br1 = (const float*)d_in[3];
    const float* W2  = (const float*)d_in[4];
    const float* bf2 = (const float*)d_in[5];
    const float* br2 = (const float*)d_in[6];
    float* out = (float*)d_out;

    const size_t elems = (size_t)MROWS * DDIM;
    const dim3 g1(N3 / 64, MROWS / 64, 2);

    if (ws_size >= 2 * elems * sizeof(float)) {
        float* xt_ws = (float*)d_ws;
        float* f_ws  = xt_ws + elems;
        gemm_gates<float><<<g1, 256, 0, stream>>>(x, W1, bf1, br1, W2, bf2, br2,
                                                  xt_ws, f_ws, out);
        scan_highway<float><<<256, 64, 0, stream>>>(x, f_ws, xt_ws, out);
    } else {
        __hip_bfloat16* xt_ws = (__hip_bfloat16*)d_ws;
        __hip_bfloat16* f_ws  = xt_ws + elems;
        gemm_gates<__hip_bfloat16><<<g1, 256, 0, stream>>>(x, W1, bf1, br1, W2, bf2, br2,
                                                           xt_ws, f_ws, out);
        scan_highway<__hip_bfloat16><<<256, 64, 0, stream>>>(x, f_ws, xt_ws, out);
    }
}

// Round 3
// 496.277 us; speedup vs baseline: 2.1885x; 2.1885x over previous
//
#include <hip/hip_runtime.h>
#include <hip/hip_bf16.h>
#include <math.h>

// GRNN on MI355X.
// Phase 1: bf16-MFMA GEMM U = x_half @ W_half (M=64000, K=256, N=768) x 2 halves.
//          Epilogue: x_tilde -> ws (bf16), f=sigmoid(.+bf) -> ws (bf16),
//          r=sigmoid(.+br) -> d_out (fp32).
// Phase 2: chunked scan: block = 64 seqs x 16 chunks (T=2000=16*125).
//          Pass1 per-chunk (P,S) -> LDS -> prefix -> Pass2 exact re-scan + highway.

constexpr int TLEN  = 2000;
constexpr int DDIM  = 512;
constexpr int HH    = 256;   // half channels
constexpr int N3    = 768;   // 3*HH
constexpr int MROWS = 64000; // 32*2000

typedef __attribute__((ext_vector_type(8))) short bf16x8;  // 8 bf16 = 4 VGPRs
typedef __attribute__((ext_vector_type(4))) float f32x4;

__device__ __forceinline__ short f2bf(float f) {
    __hip_bfloat16 h = __float2bfloat16(f);
    return *reinterpret_cast<short*>(&h);
}
__device__ __forceinline__ float sigmoidf_(float v) {
    return 1.0f / (1.0f + __expf(-v));
}

// ---------------- Phase 1: MFMA GEMM + gates ----------------
// grid (3000,1,2), block 256 (4 waves, 2x2 of 64x64 each). BK=32, 8 k-steps.
// 3000 = 6 n-tiles x 500 m-tiles per half.
__global__ __launch_bounds__(256) void gemm_gates(
    const float* __restrict__ x,
    const float* __restrict__ W1, const float* __restrict__ bf1, const float* __restrict__ br1,
    const float* __restrict__ W2, const float* __restrict__ bf2, const float* __restrict__ br2,
    __hip_bfloat16* __restrict__ xt_ws, __hip_bfloat16* __restrict__ f_ws,
    float* __restrict__ out)
{
    const int half = blockIdx.z;
    const float* __restrict__ W   = half ? W2  : W1;
    const float* __restrict__ bfb = half ? bf2 : bf1;
    const float* __restrict__ brb = half ? br2 : br1;

    // XCD swizzle: 3000 = 8*375. Each XCD gets a contiguous swz-range; n cycles
    // fast so the 6 n-tiles sharing an A-tile stay on one XCD (L2 hit on x).
    const int id  = blockIdx.x;
    const int swz = (id & 7) * 375 + (id >> 3);
    const int n0  = (swz % 6) * 128;
    const int m0  = (swz / 6) * 128;   // swz/6 in [0,499] -> m0 <= 63872

    // pad rows to 40 bf16 (80 B): fragment-read rows spread over 8 bank-groups.
    __shared__ short Als[128 * 40];  // A[m][k]  (k contiguous)
    __shared__ short Bls[128 * 40];  // B[n][k]  (k contiguous; transposed at stage)

    const int tid = threadIdx.x;
    const int l   = tid & 63;
    const int w   = tid >> 6;
    const int wm  = w >> 1, wn = w & 1;
    const int lr  = l & 15;        // fragment row (A) / col (B) / col (C)
    const int lk  = (l >> 4) * 8;  // fragment k offset

    f32x4 acc[4][4];
#pragma unroll
    for (int mi = 0; mi < 4; ++mi)
#pragma unroll
        for (int ni = 0; ni < 4; ++ni) acc[mi][ni] = (f32x4){0.f, 0.f, 0.f, 0.f};

    const int arow = tid >> 1;            // 0..127
    const int akh  = (tid & 1) * 16;      // k half of 32
    const float* aptr = x + (size_t)(m0 + arow) * DDIM + half * HH + akh;
    const int bk   = tid >> 3;            // 0..31 (k row of W)
    const int bng0 = tid & 7;             // n float4-group base

    for (int k0 = 0; k0 < HH; k0 += 32) {
        // ---- stage A: 128m x 32k, fp32 -> bf16 ----
        {
            const float4 v0 = *reinterpret_cast<const float4*>(aptr + k0 + 0);
            const float4 v1 = *reinterpret_cast<const float4*>(aptr + k0 + 4);
            const float4 v2 = *reinterpret_cast<const float4*>(aptr + k0 + 8);
            const float4 v3 = *reinterpret_cast<const float4*>(aptr + k0 + 12);
            bf16x8 p0, p1;
            p0[0]=f2bf(v0.x); p0[1]=f2bf(v0.y); p0[2]=f2bf(v0.z); p0[3]=f2bf(v0.w);
            p0[4]=f2bf(v1.x); p0[5]=f2bf(v1.y); p0[6]=f2bf(v1.z); p0[7]=f2bf(v1.w);
            p1[0]=f2bf(v2.x); p1[1]=f2bf(v2.y); p1[2]=f2bf(v2.z); p1[3]=f2bf(v2.w);
            p1[4]=f2bf(v3.x); p1[5]=f2bf(v3.y); p1[6]=f2bf(v3.z); p1[7]=f2bf(v3.w);
            short* dst = &Als[arow * 40 + akh];
            *reinterpret_cast<bf16x8*>(dst)     = p0;
            *reinterpret_cast<bf16x8*>(dst + 8) = p1;
        }
        // ---- stage B: 32k x 128n from W[k][n], write transposed [n][k] ----
#pragma unroll
        for (int i = 0; i < 4; ++i) {
            const int ng = bng0 + 8 * i;
            const float4 v = *reinterpret_cast<const float4*>(
                W + (size_t)(k0 + bk) * N3 + n0 + ng * 4);
            Bls[(ng * 4 + 0) * 40 + bk] = f2bf(v.x);
            Bls[(ng * 4 + 1) * 40 + bk] = f2bf(v.y);
            Bls[(ng * 4 + 2) * 40 + bk] = f2bf(v.z);
            Bls[(ng * 4 + 3) * 40 + bk] = f2bf(v.w);
        }
        __syncthreads();

        bf16x8 af[4], bfr[4];
#pragma unroll
        for (int mi = 0; mi < 4; ++mi)
            af[mi] = *reinterpret_cast<const bf16x8*>(
                &Als[(wm * 64 + mi * 16 + lr) * 40 + lk]);
#pragma unroll
        for (int ni = 0; ni < 4; ++ni)
            bfr[ni] = *reinterpret_cast<const bf16x8*>(
                &Bls[(wn * 64 + ni * 16 + lr) * 40 + lk]);
#pragma unroll
        for (int mi = 0; mi < 4; ++mi)
#pragma unroll
            for (int ni = 0; ni < 4; ++ni)
                acc[mi][ni] = __builtin_amdgcn_mfma_f32_16x16x32_bf16(
                    af[mi], bfr[ni], acc[mi][ni], 0, 0, 0);
        __syncthreads();
    }

    // ---- epilogue: C/D layout col=lane&15, row=(lane>>4)*4+q (m89-verified) ----
    const int seg = n0 >> 8;  // 0: x_tilde, 1: f, 2: r (128-tile within 256-seg)
#pragma unroll
    for (int mi = 0; mi < 4; ++mi) {
        const int rowb = m0 + wm * 64 + mi * 16 + (l >> 4) * 4;
#pragma unroll
        for (int ni = 0; ni < 4; ++ni) {
            const int col  = wn * 64 + ni * 16 + lr;
            const int hcol = (n0 & 255) + col;
            const f32x4 a = acc[mi][ni];
            if (seg == 0) {
#pragma unroll
                for (int q = 0; q < 4; ++q) {
                    const size_t idx = (size_t)(rowb + q) * DDIM + half * HH + hcol;
                    xt_ws[idx] = __float2bfloat16(a[q]);
                }
            } else if (seg == 1) {
                const float bias = bfb[hcol];
#pragma unroll
                for (int q = 0; q < 4; ++q) {
                    const size_t idx = (size_t)(rowb + q) * DDIM + half * HH + hcol;
                    f_ws[idx] = __float2bfloat16(sigmoidf_(a[q] + bias));
                }
            } else {
                const float bias = brb[hcol];
#pragma unroll
                for (int q = 0; q < 4; ++q) {
                    const size_t idx = (size_t)(rowb + q) * DDIM + half * HH + hcol;
                    out[idx] = sigmoidf_(a[q] + bias);
                }
            }
        }
    }
}

// ---------------- Phase 2: chunked scan + highway ----------------
// grid 256, block 1024. Block = 64 seqs x 16 chunks of 125 steps.
__global__ __launch_bounds__(1024) void scan_highway(
    const float* __restrict__ x,
    const __hip_bfloat16* __restrict__ xt_ws, const __hip_bfloat16* __restrict__ f_ws,
    float* __restrict__ out)
{
    __shared__ float smP[16][64];
    __shared__ float smS[16][64];

    const int tid = threadIdx.x;
    const int sl  = tid & 63;   // seq within block (consecutive cols -> coalesced)
    const int ch  = tid >> 6;   // chunk = wave id
    const int s   = blockIdx.x * 64 + sl;     // 0..16383
    const int b   = s >> 9;
    const int col = s & 511;
    const size_t base = (size_t)b * TLEN * DDIM + col;
    const size_t idx0 = base + (size_t)(ch * 125) * DDIM;

    // pass 1: local (P = prod f, S = local scan from c0=0); last chunk skips.
    float P = 1.f, S = 0.f;
    if (ch < 15) {
        size_t idx = idx0;
#pragma unroll 5
        for (int t = 0; t < 125; ++t, idx += DDIM) {
            const float f  = __bfloat162float(f_ws[idx]);
            const float xt = __bfloat162float(xt_ws[idx]);
            S = __builtin_fmaf(f, S, __builtin_fmaf(-f, xt, xt));
            P *= f;
        }
    }
    smP[ch][sl] = P;
    smS[ch][sl] = S;
    __syncthreads();

    // chunk-prefix: c0(ch) = S_{ch-1} + P_{ch-1} * c0(ch-1)
    float c = 0.f;
    for (int j = 0; j < ch; ++j)
        c = __builtin_fmaf(smP[j][sl], c, smS[j][sl]);

    // pass 2: exact scan with correct c0 + highway merge (r lives in out).
    size_t idx = idx0;
#pragma unroll 5
    for (int t = 0; t < 125; ++t, idx += DDIM) {
        const float f  = __bfloat162float(f_ws[idx]);
        const float xt = __bfloat162float(xt_ws[idx]);
        c = __builtin_fmaf(f, c, __builtin_fmaf(-f, xt, xt));
        const float r  = out[idx];
        const float xv = x[idx];
        out[idx] = __builtin_fmaf(r, c - xv, xv);
    }
}

extern "C" void kernel_launch(void* const* d_in, const int* in_sizes, int n_in,
                              void* d_out, int out_size, void* d_ws, size_t ws_size,
                              hipStream_t stream)
{
    const float* x   = (const float*)d_in[0];
    const float* W1  = (const float*)d_in[1];
    const float* bf1 = (const float*)d_in[2];
    const float* br1 = (const float*)d_in[3];
    const float* W2  = (const float*)d_in[4];
    const float* bf2 = (const float*)d_in[5];
    const float* br2 = (const float*)d_in[6];
    float* out = (float*)d_out;

    const size_t elems = (size_t)MROWS * DDIM;
    __hip_bfloat16* xt_ws = (__hip_bfloat16*)d_ws;
    __hip_bfloat16* f_ws  = xt_ws + elems;

    gemm_gates<<<dim3(3000, 1, 2), 256, 0, stream>>>(
        x, W1, bf1, br1, W2, bf2, br2, xt_ws, f_ws, out);
    scan_highway<<<256, 1024, 0, stream>>>(x, xt_ws, f_ws, out);
}